// Round 1
// baseline (343.916 us; speedup 1.0000x reference)
//
#include <hip/hip_runtime.h>
#include <stdint.h>

#define TOKENS 4096
#define HIDDEN 768
#define NHEADS 12
#define SEQ    1024
#define NBH    48   // B*NHEADS

typedef int   int32x4 __attribute__((ext_vector_type(4)));
typedef float f32x4   __attribute__((ext_vector_type(4)));
typedef short short8  __attribute__((ext_vector_type(8)));

// ---------------- workspace layout (bytes) ----------------
#define WBYTES   ((size_t)HIDDEN * HIDDEN)
#define OFF_COEFF ((size_t)0)
#define OFF_WQ    ((size_t)256)
#define OFF_WK    (OFF_WQ + WBYTES)
#define OFF_WV    (OFF_WK + WBYTES)
#define OFF_WO    (OFF_WV + WBYTES)
#define OFF_XQ1   (OFF_WO + WBYTES)
#define OFF_SC1   (OFF_XQ1 + (size_t)TOKENS * HIDDEN)
#define OFF_QH    (OFF_SC1 + (size_t)TOKENS * 4)
#define HB        ((size_t)NBH * SEQ * 64 * 2)
#define OFF_KH    (OFF_QH + HB)
#define OFF_VT    (OFF_KH + HB)
#define OFF_CTX   (OFF_VT + HB)
#define OFF_XQ2   (OFF_CTX + (size_t)TOKENS * HIDDEN * 4)
#define OFF_SC2   (OFF_XQ2 + (size_t)TOKENS * HIDDEN)
// total ~40.2 MB

__device__ __forceinline__ unsigned short f2bf(float f) {
  unsigned int u = __float_as_uint(f);
  u = (u + 0x7fffu + ((u >> 16) & 1u)) >> 16;
  return (unsigned short)u;
}

// ---------------- PLA coefficients (replicates np.polyfit fit on device, fp64) ---------
__global__ void init_coeffs(float* mc) {
#pragma clang fp contract(off)
  int i = threadIdx.x;
  if (i >= 12) return;
  double step_e = 10.0 / 12.0;
  double e0 = (double)i * step_e + (-10.0);
  double e1 = (i + 1 == 12) ? 0.0 : (double)(i + 1) * step_e + (-10.0);
  double n = 0.0, Sx = 0.0, Sy = 0.0, Sxy = 0.0, Sxx = 0.0;
  for (int j = 0; j <= 1000; j++) {
    double x = (j == 1000) ? 0.0 : (double)j * 0.01 + (-10.0);  // == np.linspace(-10,0,1001)
    if (x >= e0 && x <= e1) {
      double y = exp(x);
      n += 1.0; Sx += x; Sy += y; Sxy += x * y; Sxx += x * x;
    }
  }
  double det = n * Sxx - Sx * Sx;
  double m = (n * Sxy - Sx * Sy) / det;
  double c = (Sy - m * Sx) / n;
  mc[i] = (float)m;
  mc[12 + i] = (float)c;
}

// ---------------- pack int32 weights -> int8 ----------------
__global__ void pack_w(const int* __restrict__ w0, const int* __restrict__ w1,
                       const int* __restrict__ w2, const int* __restrict__ w3,
                       signed char* __restrict__ o0, signed char* __restrict__ o1,
                       signed char* __restrict__ o2, signed char* __restrict__ o3) {
  int z = blockIdx.y;
  const int* src = z == 0 ? w0 : z == 1 ? w1 : z == 2 ? w2 : w3;
  signed char* dst = z == 0 ? o0 : z == 1 ? o1 : z == 2 ? o2 : o3;
  int idx = (blockIdx.x * 256 + threadIdx.x) * 4;
  int32x4 v = *(const int32x4*)(src + idx);
  int packed = (v[0] & 255) | ((v[1] & 255) << 8) | ((v[2] & 255) << 16) | (v[3] << 24);
  *(int*)(dst + idx) = packed;
}

// ---------------- per-token dynamic int8 quantization ----------------
__global__ void quant_kernel(const float* __restrict__ x, signed char* __restrict__ xq,
                             float* __restrict__ sc) {
  int t = blockIdx.x;
  int tid = threadIdx.x;
  const float* row = x + (size_t)t * HIDDEN;
  float v0 = row[tid], v1 = row[tid + 256], v2 = row[tid + 512];
  float am = fmaxf(fabsf(v0), fmaxf(fabsf(v1), fabsf(v2)));
#pragma unroll
  for (int m = 1; m < 64; m <<= 1) am = fmaxf(am, __shfl_xor(am, m, 64));
  __shared__ float red[4];
  if ((tid & 63) == 0) red[tid >> 6] = am;
  __syncthreads();
  float total = fmaxf(fmaxf(red[0], red[1]), fmaxf(red[2], red[3]));
  float s = total / 127.0f;
  if (s == 0.0f) s = 1.0f;
  float q0 = fminf(fmaxf(rintf(v0 / s), -128.0f), 127.0f);
  float q1 = fminf(fmaxf(rintf(v1 / s), -128.0f), 127.0f);
  float q2 = fminf(fmaxf(rintf(v2 / s), -128.0f), 127.0f);
  signed char* orow = xq + (size_t)t * HIDDEN;
  orow[tid]       = (signed char)(int)q0;
  orow[tid + 256] = (signed char)(int)q1;
  orow[tid + 512] = (signed char)(int)q2;
  if (tid == 0) sc[t] = s;
}

// ---------------- QKV int8 MFMA GEMM (M=4096,N=768,K=768) ----------------
// C = A * B^T_storage : out[t][o] = sum_k xq[t][k] * w[o][k]  (exact int32)
// z=0 -> Q bf16 [b,h,s,d]; z=1 -> K bf16 [b,h,s,d]; z=2 -> V bf16 transposed [b,h,d,s]
__launch_bounds__(256)
__global__ void qkv_gemm(const signed char* __restrict__ xq, const float* __restrict__ isc,
                         const signed char* __restrict__ wq, const signed char* __restrict__ wk,
                         const signed char* __restrict__ wv,
                         const float* __restrict__ wsq, const float* __restrict__ wsk,
                         const float* __restrict__ wsv,
                         const float* __restrict__ bq, const float* __restrict__ bk,
                         const float* __restrict__ bv,
                         unsigned short* __restrict__ qh, unsigned short* __restrict__ kh,
                         unsigned short* __restrict__ vt) {
  int z = blockIdx.z;
  const signed char* w   = z == 0 ? wq  : z == 1 ? wk  : wv;
  const float*       wsc = z == 0 ? wsq : z == 1 ? wsk : wsv;
  const float*       bias= z == 0 ? bq  : z == 1 ? bk  : bv;
  unsigned short*    out = z == 0 ? qh  : z == 1 ? kh  : vt;

  int lane = threadIdx.x & 63, wave = threadIdx.x >> 6;
  int lr = lane & 15, lg = lane >> 4;
  int mbase = blockIdx.x * 128 + (wave >> 1) * 64;
  int nbase = blockIdx.y * 128 + (wave & 1) * 64;

  int32x4 acc[4][4];
#pragma unroll
  for (int i = 0; i < 4; i++)
#pragma unroll
    for (int j = 0; j < 4; j++) acc[i][j] = (int32x4){0, 0, 0, 0};

  const signed char* aP = xq + (size_t)(mbase + lr) * HIDDEN + lg * 16;
  const signed char* bP = w  + (size_t)(nbase + lr) * HIDDEN + lg * 16;
  for (int ks = 0; ks < 12; ks++) {
    int32x4 af[4], bf[4];
#pragma unroll
    for (int i = 0; i < 4; i++) af[i] = *(const int32x4*)(aP + (size_t)i * 16 * HIDDEN + ks * 64);
#pragma unroll
    for (int j = 0; j < 4; j++) bf[j] = *(const int32x4*)(bP + (size_t)j * 16 * HIDDEN + ks * 64);
#pragma unroll
    for (int i = 0; i < 4; i++)
#pragma unroll
      for (int j = 0; j < 4; j++)
        acc[i][j] = __builtin_amdgcn_mfma_i32_16x16x64_i8(af[i], bf[j], acc[i][j], 0, 0, 0);
  }

#pragma unroll
  for (int j = 0; j < 4; j++) {
    int col = nbase + j * 16 + lr;
    float wsv_ = wsc[col], bv_ = bias[col];
    int h = col >> 6, d = col & 63;
#pragma unroll
    for (int i = 0; i < 4; i++) {
#pragma unroll
      for (int r = 0; r < 4; r++) {
        int trow = mbase + i * 16 + lg * 4 + r;
        float v = (float)acc[i][j][r] * wsv_ * isc[trow] + bv_;
        int bb = trow >> 10, ss = trow & 1023;
        size_t off;
        if (z < 2) off = (((size_t)(bb * NHEADS + h)) * SEQ + ss) * 64 + d;
        else       off = (((size_t)(bb * NHEADS + h)) * 64 + d) * SEQ + ss;
        out[off] = f2bf(v);
      }
    }
  }
}

// ---------------- O-proj int8 MFMA GEMM -> fp32 d_out ----------------
__launch_bounds__(256)
__global__ void o_gemm(const signed char* __restrict__ xq, const float* __restrict__ isc,
                       const signed char* __restrict__ w, const float* __restrict__ wsc,
                       const float* __restrict__ bias, float* __restrict__ out) {
  int lane = threadIdx.x & 63, wave = threadIdx.x >> 6;
  int lr = lane & 15, lg = lane >> 4;
  int mbase = blockIdx.x * 128 + (wave >> 1) * 64;
  int nbase = blockIdx.y * 128 + (wave & 1) * 64;

  int32x4 acc[4][4];
#pragma unroll
  for (int i = 0; i < 4; i++)
#pragma unroll
    for (int j = 0; j < 4; j++) acc[i][j] = (int32x4){0, 0, 0, 0};

  const signed char* aP = xq + (size_t)(mbase + lr) * HIDDEN + lg * 16;
  const signed char* bP = w  + (size_t)(nbase + lr) * HIDDEN + lg * 16;
  for (int ks = 0; ks < 12; ks++) {
    int32x4 af[4], bf[4];
#pragma unroll
    for (int i = 0; i < 4; i++) af[i] = *(const int32x4*)(aP + (size_t)i * 16 * HIDDEN + ks * 64);
#pragma unroll
    for (int j = 0; j < 4; j++) bf[j] = *(const int32x4*)(bP + (size_t)j * 16 * HIDDEN + ks * 64);
#pragma unroll
    for (int i = 0; i < 4; i++)
#pragma unroll
      for (int j = 0; j < 4; j++)
        acc[i][j] = __builtin_amdgcn_mfma_i32_16x16x64_i8(af[i], bf[j], acc[i][j], 0, 0, 0);
  }

#pragma unroll
  for (int j = 0; j < 4; j++) {
    int col = nbase + j * 16 + lr;
    float wsv_ = wsc[col], bv_ = bias[col];
#pragma unroll
    for (int i = 0; i < 4; i++) {
#pragma unroll
      for (int r = 0; r < 4; r++) {
        int trow = mbase + i * 16 + lg * 4 + r;
        float v = (float)acc[i][j][r] * wsv_ * isc[trow] + bv_;
        out[(size_t)trow * HIDDEN + col] = v;
      }
    }
  }
}

// ---------------- attention: 2-pass PLA softmax, bf16 MFMA ----------------
// grid (16 qtiles, 48 bh), 256 thr; each wave owns 16 q-rows.
__launch_bounds__(256)
__global__ void attn_kernel(const unsigned short* __restrict__ qh,
                            const unsigned short* __restrict__ kh,
                            const unsigned short* __restrict__ vt,
                            const float* __restrict__ mask,
                            const float* __restrict__ coeff,
                            float* __restrict__ ctx) {
  __shared__ float2 lmc[12];
  __shared__ __align__(16) unsigned short plds[4][16][40];  // padded: 80B row stride
  int tid = threadIdx.x;
  if (tid < 12) lmc[tid] = make_float2(coeff[tid], coeff[12 + tid]);
  __syncthreads();

  int bh = blockIdx.y, b = bh / NHEADS, h = bh % NHEADS;
  int lane = tid & 63, wave = tid >> 6;
  int lr = lane & 15, lg = lane >> 4;
  int qbase = blockIdx.x * 64 + wave * 16;

  const unsigned short* qrow   = qh + ((size_t)bh * SEQ + qbase) * 64;
  const unsigned short* khead  = kh + (size_t)bh * SEQ * 64;
  const unsigned short* vthead = vt + (size_t)bh * 64 * SEQ;
  const float* mrow = mask + b * SEQ;

  short8 qa0 = *(const short8*)(qrow + lr * 64 + lg * 8);
  short8 qa1 = *(const short8*)(qrow + lr * 64 + 32 + lg * 8);

  // pass A: row max of (qk*0.125 + mask)
  float rmax[4] = {-3.0e38f, -3.0e38f, -3.0e38f, -3.0e38f};
  for (int kt = 0; kt < 64; kt++) {
    const unsigned short* kr = khead + (size_t)(kt * 16 + lr) * 64 + lg * 8;
    short8 kb0 = *(const short8*)kr;
    short8 kb1 = *(const short8*)(kr + 32);
    f32x4 a = {0.f, 0.f, 0.f, 0.f};
    a = __builtin_amdgcn_mfma_f32_16x16x32_bf16(qa0, kb0, a, 0, 0, 0);
    a = __builtin_amdgcn_mfma_f32_16x16x32_bf16(qa1, kb1, a, 0, 0, 0);
    float mk = mrow[kt * 16 + lr];
#pragma unroll
    for (int r = 0; r < 4; r++) rmax[r] = fmaxf(rmax[r], a[r] * 0.125f + mk);
  }
#pragma unroll
  for (int r = 0; r < 4; r++)
#pragma unroll
    for (int m = 1; m < 16; m <<= 1)
      rmax[r] = fmaxf(rmax[r], __shfl_xor(rmax[r], m, 64));

  // pass B: recompute scores, PLA exp, row sum, PV accumulate
  f32x4 pacc[4];
#pragma unroll
  for (int n = 0; n < 4; n++) pacc[n] = (f32x4){0.f, 0.f, 0.f, 0.f};
  float rsum[4] = {0.f, 0.f, 0.f, 0.f};

  for (int ch = 0; ch < 32; ch++) {
    const unsigned short* kr0 = khead + (size_t)(ch * 32 + lr) * 64 + lg * 8;
    const unsigned short* kr1 = kr0 + 16 * 64;
    f32x4 s0 = {0.f, 0.f, 0.f, 0.f}, s1 = {0.f, 0.f, 0.f, 0.f};
    s0 = __builtin_amdgcn_mfma_f32_16x16x32_bf16(qa0, *(const short8*)kr0, s0, 0, 0, 0);
    s0 = __builtin_amdgcn_mfma_f32_16x16x32_bf16(qa1, *(const short8*)(kr0 + 32), s0, 0, 0, 0);
    s1 = __builtin_amdgcn_mfma_f32_16x16x32_bf16(qa0, *(const short8*)kr1, s1, 0, 0, 0);
    s1 = __builtin_amdgcn_mfma_f32_16x16x32_bf16(qa1, *(const short8*)(kr1 + 32), s1, 0, 0, 0);
    float mk0 = mrow[ch * 32 + lr], mk1 = mrow[ch * 32 + 16 + lr];
#pragma unroll
    for (int r = 0; r < 4; r++) {
      float x0 = fminf(fmaxf(s0[r] * 0.125f + mk0 - rmax[r], -10.f), 0.f);
      int i0 = (int)((x0 + 10.f) * 1.2f); i0 = i0 > 10 ? 10 : i0;
      float2 mc0 = lmc[i0];
      float p0 = mc0.x * x0 + mc0.y;
      rsum[r] += p0;
      plds[wave][lg * 4 + r][lr] = f2bf(p0);
      float x1 = fminf(fmaxf(s1[r] * 0.125f + mk1 - rmax[r], -10.f), 0.f);
      int i1 = (int)((x1 + 10.f) * 1.2f); i1 = i1 > 10 ? 10 : i1;
      float2 mc1 = lmc[i1];
      float p1 = mc1.x * x1 + mc1.y;
      rsum[r] += p1;
      plds[wave][lg * 4 + r][16 + lr] = f2bf(p1);
    }
    __asm__ volatile("s_waitcnt lgkmcnt(0)" ::: "memory");  // cross-lane P transpose via LDS
    short8 pa = *(const short8*)&plds[wave][lr][lg * 8];
#pragma unroll
    for (int n = 0; n < 4; n++) {
      const unsigned short* vr = vthead + (size_t)(n * 16 + lr) * SEQ + ch * 32 + lg * 8;
      short8 vb = *(const short8*)vr;
      pacc[n] = __builtin_amdgcn_mfma_f32_16x16x32_bf16(pa, vb, pacc[n], 0, 0, 0);
    }
  }

#pragma unroll
  for (int r = 0; r < 4; r++)
#pragma unroll
    for (int m = 1; m < 16; m <<= 1) rsum[r] += __shfl_xor(rsum[r], m, 64);

#pragma unroll
  for (int n = 0; n < 4; n++) {
#pragma unroll
    for (int r = 0; r < 4; r++) {
      int qr = qbase + lg * 4 + r;
      float denom = rsum[r] + 1e-9f;
      ctx[((size_t)b * SEQ + qr) * HIDDEN + h * 64 + n * 16 + lr] = pacc[n][r] / denom;
    }
  }
}

// ---------------- launch ----------------
extern "C" void kernel_launch(void* const* d_in, const int* in_sizes, int n_in,
                              void* d_out, int out_size, void* d_ws, size_t ws_size,
                              hipStream_t stream) {
  const float* hidden = (const float*)d_in[0];
  const float* mask   = (const float*)d_in[1];
  const int*   wq  = (const int*)d_in[2];
  const float* wsq = (const float*)d_in[3];
  const float* bq  = (const float*)d_in[4];
  const int*   wk  = (const int*)d_in[5];
  const float* wsk = (const float*)d_in[6];
  const float* bk  = (const float*)d_in[7];
  const int*   wv  = (const int*)d_in[8];
  const float* wsv = (const float*)d_in[9];
  const float* bv  = (const float*)d_in[10];
  const int*   wo  = (const int*)d_in[11];
  const float* wso = (const float*)d_in[12];
  const float* bo  = (const float*)d_in[13];

  char* ws = (char*)d_ws;
  float*          coeff = (float*)(ws + OFF_COEFF);
  signed char*    pwq   = (signed char*)(ws + OFF_WQ);
  signed char*    pwk   = (signed char*)(ws + OFF_WK);
  signed char*    pwv   = (signed char*)(ws + OFF_WV);
  signed char*    pwo   = (signed char*)(ws + OFF_WO);
  signed char*    xq1   = (signed char*)(ws + OFF_XQ1);
  float*          sc1   = (float*)(ws + OFF_SC1);
  unsigned short* qhp   = (unsigned short*)(ws + OFF_QH);
  unsigned short* khp   = (unsigned short*)(ws + OFF_KH);
  unsigned short* vtp   = (unsigned short*)(ws + OFF_VT);
  float*          ctxp  = (float*)(ws + OFF_CTX);
  signed char*    xq2   = (signed char*)(ws + OFF_XQ2);
  float*          sc2   = (float*)(ws + OFF_SC2);

  init_coeffs<<<1, 64, 0, stream>>>(coeff);
  pack_w<<<dim3(576, 4), 256, 0, stream>>>(wq, wk, wv, wo, pwq, pwk, pwv, pwo);
  quant_kernel<<<TOKENS, 256, 0, stream>>>(hidden, xq1, sc1);
  qkv_gemm<<<dim3(32, 6, 3), 256, 0, stream>>>(xq1, sc1, pwq, pwk, pwv,
                                               wsq, wsk, wsv, bq, bk, bv,
                                               qhp, khp, vtp);
  attn_kernel<<<dim3(16, 48), 256, 0, stream>>>(qhp, khp, vtp, mask, coeff, ctxp);
  quant_kernel<<<TOKENS, 256, 0, stream>>>(ctxp, xq2, sc2);
  o_gemm<<<dim3(32, 6, 1), 256, 0, stream>>>(xq2, sc2, pwo, wso, bo, (float*)d_out);
}

// Round 2
// 218.931 us; speedup vs baseline: 1.5709x; 1.5709x over previous
//
#include <hip/hip_runtime.h>
#include <stdint.h>
#include <cmath>

#define TOKENS 4096
#define HIDDEN 768
#define NHEADS 12
#define SEQ    1024
#define NBH    48   // B*NHEADS

typedef int   int32x4 __attribute__((ext_vector_type(4)));
typedef float f32x4   __attribute__((ext_vector_type(4)));
typedef short short8  __attribute__((ext_vector_type(8)));

struct PlaCoeffs { float m[12]; float c[12]; };

// ---------------- workspace layout (bytes) ----------------
#define WBYTES   ((size_t)HIDDEN * HIDDEN)
#define OFF_WQ    ((size_t)256)
#define OFF_WK    (OFF_WQ + WBYTES)
#define OFF_WV    (OFF_WK + WBYTES)
#define OFF_WO    (OFF_WV + WBYTES)
#define OFF_XQ1   (OFF_WO + WBYTES)
#define OFF_SC1   (OFF_XQ1 + (size_t)TOKENS * HIDDEN)
#define OFF_QH    (OFF_SC1 + (size_t)TOKENS * 4)
#define HB        ((size_t)NBH * SEQ * 64 * 2)
#define OFF_KH    (OFF_QH + HB)
#define OFF_VT    (OFF_KH + HB)
#define OFF_CTX   (OFF_VT + HB)
#define OFF_XQ2   (OFF_CTX + (size_t)TOKENS * HIDDEN * 4)
#define OFF_SC2   (OFF_XQ2 + (size_t)TOKENS * HIDDEN)
// total ~40.2 MB

__device__ __forceinline__ unsigned short f2bf(float f) {
  unsigned int u = __float_as_uint(f);
  u = (u + 0x7fffu + ((u >> 16) & 1u)) >> 16;
  return (unsigned short)u;
}

// ---------------- PLA coefficients: host-side, replicates np.polyfit fit ----------------
static PlaCoeffs compute_pla_coeffs() {
  PlaCoeffs out;
  const double step_e = 10.0 / 12.0;
  for (int i = 0; i < 12; i++) {
    double e0 = (double)i * step_e + (-10.0);
    double e1 = (i + 1 == 12) ? 0.0 : (double)(i + 1) * step_e + (-10.0);
    double n = 0.0, Sx = 0.0, Sy = 0.0, Sxy = 0.0, Sxx = 0.0;
    for (int j = 0; j <= 1000; j++) {
      double x = (j == 1000) ? 0.0 : (double)j * 0.01 + (-10.0);  // == np.linspace(-10,0,1001)
      if (x >= e0 && x <= e1) {
        double y = std::exp(x);
        n += 1.0; Sx += x; Sy += y; Sxy += x * y; Sxx += x * x;
      }
    }
    double det = n * Sxx - Sx * Sx;
    double m = (n * Sxy - Sx * Sy) / det;
    double c = (Sy - m * Sx) / n;
    out.m[i] = (float)m;
    out.c[i] = (float)c;
  }
  return out;
}
static const PlaCoeffs g_pla = compute_pla_coeffs();

// ---------------- pack int32 weights -> int8 ----------------
__global__ void pack_w(const int* __restrict__ w0, const int* __restrict__ w1,
                       const int* __restrict__ w2, const int* __restrict__ w3,
                       signed char* __restrict__ o0, signed char* __restrict__ o1,
                       signed char* __restrict__ o2, signed char* __restrict__ o3) {
  int z = blockIdx.y;
  const int* src = z == 0 ? w0 : z == 1 ? w1 : z == 2 ? w2 : w3;
  signed char* dst = z == 0 ? o0 : z == 1 ? o1 : z == 2 ? o2 : o3;
  int idx = (blockIdx.x * 256 + threadIdx.x) * 4;
  int32x4 v = *(const int32x4*)(src + idx);
  int packed = (v[0] & 255) | ((v[1] & 255) << 8) | ((v[2] & 255) << 16) | (v[3] << 24);
  *(int*)(dst + idx) = packed;
}

// ---------------- per-token dynamic int8 quantization ----------------
__global__ void quant_kernel(const float* __restrict__ x, signed char* __restrict__ xq,
                             float* __restrict__ sc) {
  int t = blockIdx.x;
  int tid = threadIdx.x;
  const float* row = x + (size_t)t * HIDDEN;
  float v0 = row[tid], v1 = row[tid + 256], v2 = row[tid + 512];
  float am = fmaxf(fabsf(v0), fmaxf(fabsf(v1), fabsf(v2)));
#pragma unroll
  for (int m = 1; m < 64; m <<= 1) am = fmaxf(am, __shfl_xor(am, m, 64));
  __shared__ float red[4];
  if ((tid & 63) == 0) red[tid >> 6] = am;
  __syncthreads();
  float total = fmaxf(fmaxf(red[0], red[1]), fmaxf(red[2], red[3]));
  float s = total / 127.0f;
  if (s == 0.0f) s = 1.0f;
  float q0 = fminf(fmaxf(rintf(v0 / s), -128.0f), 127.0f);
  float q1 = fminf(fmaxf(rintf(v1 / s), -128.0f), 127.0f);
  float q2 = fminf(fmaxf(rintf(v2 / s), -128.0f), 127.0f);
  signed char* orow = xq + (size_t)t * HIDDEN;
  orow[tid]       = (signed char)(int)q0;
  orow[tid + 256] = (signed char)(int)q1;
  orow[tid + 512] = (signed char)(int)q2;
  if (tid == 0) sc[t] = s;
}

// ---------------- QKV int8 MFMA GEMM (M=4096,N=768,K=768) ----------------
// C = A * B^T_storage : out[t][o] = sum_k xq[t][k] * w[o][k]  (exact int32)
// z=0 -> Q bf16 [b,h,s,d]; z=1 -> K bf16 [b,h,s,d]; z=2 -> V bf16 transposed [b,h,d,s]
__launch_bounds__(256)
__global__ void qkv_gemm(const signed char* __restrict__ xq, const float* __restrict__ isc,
                         const signed char* __restrict__ wq, const signed char* __restrict__ wk,
                         const signed char* __restrict__ wv,
                         const float* __restrict__ wsq, const float* __restrict__ wsk,
                         const float* __restrict__ wsv,
                         const float* __restrict__ bq, const float* __restrict__ bk,
                         const float* __restrict__ bv,
                         unsigned short* __restrict__ qh, unsigned short* __restrict__ kh,
                         unsigned short* __restrict__ vt) {
  int z = blockIdx.z;
  const signed char* w   = z == 0 ? wq  : z == 1 ? wk  : wv;
  const float*       wsc = z == 0 ? wsq : z == 1 ? wsk : wsv;
  const float*       bias= z == 0 ? bq  : z == 1 ? bk  : bv;
  unsigned short*    out = z == 0 ? qh  : z == 1 ? kh  : vt;

  int lane = threadIdx.x & 63, wave = threadIdx.x >> 6;
  int lr = lane & 15, lg = lane >> 4;
  int mbase = blockIdx.x * 128 + (wave >> 1) * 64;
  int nbase = blockIdx.y * 128 + (wave & 1) * 64;

  int32x4 acc[4][4];
#pragma unroll
  for (int i = 0; i < 4; i++)
#pragma unroll
    for (int j = 0; j < 4; j++) acc[i][j] = (int32x4){0, 0, 0, 0};

  const signed char* aP = xq + (size_t)(mbase + lr) * HIDDEN + lg * 16;
  const signed char* bP = w  + (size_t)(nbase + lr) * HIDDEN + lg * 16;
  for (int ks = 0; ks < 12; ks++) {
    int32x4 af[4], bf[4];
#pragma unroll
    for (int i = 0; i < 4; i++) af[i] = *(const int32x4*)(aP + (size_t)i * 16 * HIDDEN + ks * 64);
#pragma unroll
    for (int j = 0; j < 4; j++) bf[j] = *(const int32x4*)(bP + (size_t)j * 16 * HIDDEN + ks * 64);
#pragma unroll
    for (int i = 0; i < 4; i++)
#pragma unroll
      for (int j = 0; j < 4; j++)
        acc[i][j] = __builtin_amdgcn_mfma_i32_16x16x64_i8(af[i], bf[j], acc[i][j], 0, 0, 0);
  }

#pragma unroll
  for (int j = 0; j < 4; j++) {
    int col = nbase + j * 16 + lr;
    float wsv_ = wsc[col], bv_ = bias[col];
    int h = col >> 6, d = col & 63;
#pragma unroll
    for (int i = 0; i < 4; i++) {
#pragma unroll
      for (int r = 0; r < 4; r++) {
        int trow = mbase + i * 16 + lg * 4 + r;
        float v = (float)acc[i][j][r] * wsv_ * isc[trow] + bv_;
        int bb = trow >> 10, ss = trow & 1023;
        size_t off;
        if (z < 2) off = (((size_t)(bb * NHEADS + h)) * SEQ + ss) * 64 + d;
        else       off = (((size_t)(bb * NHEADS + h)) * 64 + d) * SEQ + ss;
        out[off] = f2bf(v);
      }
    }
  }
}

// ---------------- O-proj int8 MFMA GEMM -> fp32 d_out ----------------
__launch_bounds__(256)
__global__ void o_gemm(const signed char* __restrict__ xq, const float* __restrict__ isc,
                       const signed char* __restrict__ w, const float* __restrict__ wsc,
                       const float* __restrict__ bias, float* __restrict__ out) {
  int lane = threadIdx.x & 63, wave = threadIdx.x >> 6;
  int lr = lane & 15, lg = lane >> 4;
  int mbase = blockIdx.x * 128 + (wave >> 1) * 64;
  int nbase = blockIdx.y * 128 + (wave & 1) * 64;

  int32x4 acc[4][4];
#pragma unroll
  for (int i = 0; i < 4; i++)
#pragma unroll
    for (int j = 0; j < 4; j++) acc[i][j] = (int32x4){0, 0, 0, 0};

  const signed char* aP = xq + (size_t)(mbase + lr) * HIDDEN + lg * 16;
  const signed char* bP = w  + (size_t)(nbase + lr) * HIDDEN + lg * 16;
  for (int ks = 0; ks < 12; ks++) {
    int32x4 af[4], bf[4];
#pragma unroll
    for (int i = 0; i < 4; i++) af[i] = *(const int32x4*)(aP + (size_t)i * 16 * HIDDEN + ks * 64);
#pragma unroll
    for (int j = 0; j < 4; j++) bf[j] = *(const int32x4*)(bP + (size_t)j * 16 * HIDDEN + ks * 64);
#pragma unroll
    for (int i = 0; i < 4; i++)
#pragma unroll
      for (int j = 0; j < 4; j++)
        acc[i][j] = __builtin_amdgcn_mfma_i32_16x16x64_i8(af[i], bf[j], acc[i][j], 0, 0, 0);
  }

#pragma unroll
  for (int j = 0; j < 4; j++) {
    int col = nbase + j * 16 + lr;
    float wsv_ = wsc[col], bv_ = bias[col];
#pragma unroll
    for (int i = 0; i < 4; i++) {
#pragma unroll
      for (int r = 0; r < 4; r++) {
        int trow = mbase + i * 16 + lg * 4 + r;
        float v = (float)acc[i][j][r] * wsv_ * isc[trow] + bv_;
        out[(size_t)trow * HIDDEN + col] = v;
      }
    }
  }
}

// ---------------- attention: 2-pass PLA softmax, bf16 MFMA ----------------
// grid (16 qtiles, 48 bh), 256 thr; each wave owns 16 q-rows.
__launch_bounds__(256)
__global__ void attn_kernel(const unsigned short* __restrict__ qh,
                            const unsigned short* __restrict__ kh,
                            const unsigned short* __restrict__ vt,
                            const float* __restrict__ mask,
                            const PlaCoeffs cf,
                            float* __restrict__ ctx) {
  __shared__ float2 lmc[12];
  __shared__ __align__(16) unsigned short plds[4][16][40];  // padded: 80B row stride
  int tid = threadIdx.x;
  if (tid == 0) {
#pragma unroll
    for (int i = 0; i < 12; i++) lmc[i] = make_float2(cf.m[i], cf.c[i]);
  }
  __syncthreads();

  int bh = blockIdx.y, b = bh / NHEADS, h = bh % NHEADS;
  int lane = tid & 63, wave = tid >> 6;
  int lr = lane & 15, lg = lane >> 4;
  int qbase = blockIdx.x * 64 + wave * 16;

  const unsigned short* qrow   = qh + ((size_t)bh * SEQ + qbase) * 64;
  const unsigned short* khead  = kh + (size_t)bh * SEQ * 64;
  const unsigned short* vthead = vt + (size_t)bh * 64 * SEQ;
  const float* mrow = mask + b * SEQ;

  short8 qa0 = *(const short8*)(qrow + lr * 64 + lg * 8);
  short8 qa1 = *(const short8*)(qrow + lr * 64 + 32 + lg * 8);

  // pass A: row max of (qk*0.125 + mask)
  float rmax[4] = {-3.0e38f, -3.0e38f, -3.0e38f, -3.0e38f};
  for (int kt = 0; kt < 64; kt++) {
    const unsigned short* kr = khead + (size_t)(kt * 16 + lr) * 64 + lg * 8;
    short8 kb0 = *(const short8*)kr;
    short8 kb1 = *(const short8*)(kr + 32);
    f32x4 a = {0.f, 0.f, 0.f, 0.f};
    a = __builtin_amdgcn_mfma_f32_16x16x32_bf16(qa0, kb0, a, 0, 0, 0);
    a = __builtin_amdgcn_mfma_f32_16x16x32_bf16(qa1, kb1, a, 0, 0, 0);
    float mk = mrow[kt * 16 + lr];
#pragma unroll
    for (int r = 0; r < 4; r++) rmax[r] = fmaxf(rmax[r], a[r] * 0.125f + mk);
  }
#pragma unroll
  for (int r = 0; r < 4; r++)
#pragma unroll
    for (int m = 1; m < 16; m <<= 1)
      rmax[r] = fmaxf(rmax[r], __shfl_xor(rmax[r], m, 64));

  // pass B: recompute scores, PLA exp, row sum, PV accumulate
  f32x4 pacc[4];
#pragma unroll
  for (int n = 0; n < 4; n++) pacc[n] = (f32x4){0.f, 0.f, 0.f, 0.f};
  float rsum[4] = {0.f, 0.f, 0.f, 0.f};

  for (int ch = 0; ch < 32; ch++) {
    const unsigned short* kr0 = khead + (size_t)(ch * 32 + lr) * 64 + lg * 8;
    const unsigned short* kr1 = kr0 + 16 * 64;
    f32x4 s0 = {0.f, 0.f, 0.f, 0.f}, s1 = {0.f, 0.f, 0.f, 0.f};
    s0 = __builtin_amdgcn_mfma_f32_16x16x32_bf16(qa0, *(const short8*)kr0, s0, 0, 0, 0);
    s0 = __builtin_amdgcn_mfma_f32_16x16x32_bf16(qa1, *(const short8*)(kr0 + 32), s0, 0, 0, 0);
    s1 = __builtin_amdgcn_mfma_f32_16x16x32_bf16(qa0, *(const short8*)kr1, s1, 0, 0, 0);
    s1 = __builtin_amdgcn_mfma_f32_16x16x32_bf16(qa1, *(const short8*)(kr1 + 32), s1, 0, 0, 0);
    float mk0 = mrow[ch * 32 + lr], mk1 = mrow[ch * 32 + 16 + lr];
#pragma unroll
    for (int r = 0; r < 4; r++) {
      float x0 = fminf(fmaxf(s0[r] * 0.125f + mk0 - rmax[r], -10.f), 0.f);
      int i0 = (int)((x0 + 10.f) * 1.2f); i0 = i0 > 10 ? 10 : i0;
      float2 mc0 = lmc[i0];
      float p0 = mc0.x * x0 + mc0.y;
      rsum[r] += p0;
      plds[wave][lg * 4 + r][lr] = f2bf(p0);
      float x1 = fminf(fmaxf(s1[r] * 0.125f + mk1 - rmax[r], -10.f), 0.f);
      int i1 = (int)((x1 + 10.f) * 1.2f); i1 = i1 > 10 ? 10 : i1;
      float2 mc1 = lmc[i1];
      float p1 = mc1.x * x1 + mc1.y;
      rsum[r] += p1;
      plds[wave][lg * 4 + r][16 + lr] = f2bf(p1);
    }
    __asm__ volatile("s_waitcnt lgkmcnt(0)" ::: "memory");  // cross-lane P transpose via LDS
    short8 pa = *(const short8*)&plds[wave][lr][lg * 8];
#pragma unroll
    for (int n = 0; n < 4; n++) {
      const unsigned short* vr = vthead + (size_t)(n * 16 + lr) * SEQ + ch * 32 + lg * 8;
      short8 vb = *(const short8*)vr;
      pacc[n] = __builtin_amdgcn_mfma_f32_16x16x32_bf16(pa, vb, pacc[n], 0, 0, 0);
    }
  }

#pragma unroll
  for (int r = 0; r < 4; r++)
#pragma unroll
    for (int m = 1; m < 16; m <<= 1) rsum[r] += __shfl_xor(rsum[r], m, 64);

#pragma unroll
  for (int n = 0; n < 4; n++) {
#pragma unroll
    for (int r = 0; r < 4; r++) {
      int qr = qbase + lg * 4 + r;
      float denom = rsum[r] + 1e-9f;
      ctx[((size_t)b * SEQ + qr) * HIDDEN + h * 64 + n * 16 + lr] = pacc[n][r] / denom;
    }
  }
}

// ---------------- launch ----------------
extern "C" void kernel_launch(void* const* d_in, const int* in_sizes, int n_in,
                              void* d_out, int out_size, void* d_ws, size_t ws_size,
                              hipStream_t stream) {
  const float* hidden = (const float*)d_in[0];
  const float* mask   = (const float*)d_in[1];
  const int*   wq  = (const int*)d_in[2];
  const float* wsq = (const float*)d_in[3];
  const float* bq  = (const float*)d_in[4];
  const int*   wk  = (const int*)d_in[5];
  const float* wsk = (const float*)d_in[6];
  const float* bk  = (const float*)d_in[7];
  const int*   wv  = (const int*)d_in[8];
  const float* wsv = (const float*)d_in[9];
  const float* bv  = (const float*)d_in[10];
  const int*   wo  = (const int*)d_in[11];
  const float* wso = (const float*)d_in[12];
  const float* bo  = (const float*)d_in[13];

  char* ws = (char*)d_ws;
  signed char*    pwq   = (signed char*)(ws + OFF_WQ);
  signed char*    pwk   = (signed char*)(ws + OFF_WK);
  signed char*    pwv   = (signed char*)(ws + OFF_WV);
  signed char*    pwo   = (signed char*)(ws + OFF_WO);
  signed char*    xq1   = (signed char*)(ws + OFF_XQ1);
  float*          sc1   = (float*)(ws + OFF_SC1);
  unsigned short* qhp   = (unsigned short*)(ws + OFF_QH);
  unsigned short* khp   = (unsigned short*)(ws + OFF_KH);
  unsigned short* vtp   = (unsigned short*)(ws + OFF_VT);
  float*          ctxp  = (float*)(ws + OFF_CTX);
  signed char*    xq2   = (signed char*)(ws + OFF_XQ2);
  float*          sc2   = (float*)(ws + OFF_SC2);

  pack_w<<<dim3(576, 4), 256, 0, stream>>>(wq, wk, wv, wo, pwq, pwk, pwv, pwo);
  quant_kernel<<<TOKENS, 256, 0, stream>>>(hidden, xq1, sc1);
  qkv_gemm<<<dim3(32, 6, 3), 256, 0, stream>>>(xq1, sc1, pwq, pwk, pwv,
                                               wsq, wsk, wsv, bq, bk, bv,
                                               qhp, khp, vtp);
  attn_kernel<<<dim3(16, 48), 256, 0, stream>>>(qhp, khp, vtp, mask, g_pla, ctxp);
  quant_kernel<<<TOKENS, 256, 0, stream>>>(hidden /*dummy replaced below*/, xq2, sc2);
  // NOTE: second quant must read ctx, not hidden — corrected call:
  quant_kernel<<<TOKENS, 256, 0, stream>>>(ctxp, xq2, sc2);
  o_gemm<<<dim3(32, 6, 1), 256, 0, stream>>>(xq2, sc2, pwo, wso, bo, (float*)d_out);
}